// Round 1
// baseline (687.629 us; speedup 1.0000x reference)
//
#include <hip/hip_runtime.h>
#include <math.h>

#define CCH 32   // channels
#define LPS 8    // lanes per segment (32 channels / 4 per float4)

// Pass 1: start[s] = lower_bound(ids, s) for s in [0, M]
__global__ void seg_starts_kernel(const int* __restrict__ ids,
                                  int* __restrict__ start,
                                  int N, int M) {
    int i = blockIdx.x * blockDim.x + threadIdx.x;
    if (i > N) return;
    if (i == 0) {
        int hi = ids[0];
        for (int s = 0; s <= hi; ++s) start[s] = 0;
    } else if (i == N) {
        int lo = ids[N - 1];
        for (int s = lo + 1; s <= M; ++s) start[s] = N;
    } else {
        int prev = ids[i - 1];
        int cur  = ids[i];
        for (int s = prev + 1; s <= cur; ++s) start[s] = i;
    }
}

__device__ __forceinline__ float4 f4max(float4 a, float4 b) {
    a.x = fmaxf(a.x, b.x);
    a.y = fmaxf(a.y, b.y);
    a.z = fmaxf(a.z, b.z);
    a.w = fmaxf(a.w, b.w);
    return a;
}

__device__ __forceinline__ float zinf(float v) {
    return isinf(v) ? 0.0f : v;
}

// Pass 2: one 8-lane group per segment; each lane holds 4 channels (float4).
__global__ void seg_max_kernel(const float4* __restrict__ feat,
                               const int* __restrict__ start,
                               float4* __restrict__ out, int M) {
    int t = blockIdx.x * blockDim.x + threadIdx.x;
    int g = t >> 3;       // segment id
    int lane = t & (LPS - 1);
    if (g >= M) return;

    int s0 = start[g];
    int s1 = start[g + 1];

    float4 acc = make_float4(-INFINITY, -INFINITY, -INFINITY, -INFINITY);
    const float4* p = feat + (size_t)s0 * LPS + lane;
    for (int r = s0; r < s1; ++r) {
        acc = f4max(acc, *p);
        p += LPS;
    }
    acc.x = zinf(acc.x);
    acc.y = zinf(acc.y);
    acc.z = zinf(acc.z);
    acc.w = zinf(acc.w);
    out[(size_t)g * LPS + lane] = acc;
}

// Fallback (no workspace): binary-search the row range per segment.
__device__ __forceinline__ int lower_bound_dev(const int* __restrict__ ids,
                                               int n, int key) {
    int lo = 0, hi = n;
    while (lo < hi) {
        int mid = (lo + hi) >> 1;
        if (ids[mid] < key) lo = mid + 1;
        else hi = mid;
    }
    return lo;
}

__global__ void seg_max_search_kernel(const float4* __restrict__ feat,
                                      const int* __restrict__ ids,
                                      float4* __restrict__ out,
                                      int N, int M) {
    int t = blockIdx.x * blockDim.x + threadIdx.x;
    int g = t >> 3;
    int lane = t & (LPS - 1);
    if (g >= M) return;

    int s0 = lower_bound_dev(ids, N, g);
    int s1 = lower_bound_dev(ids, N, g + 1);

    float4 acc = make_float4(-INFINITY, -INFINITY, -INFINITY, -INFINITY);
    const float4* p = feat + (size_t)s0 * LPS + lane;
    for (int r = s0; r < s1; ++r) {
        acc = f4max(acc, *p);
        p += LPS;
    }
    acc.x = zinf(acc.x);
    acc.y = zinf(acc.y);
    acc.z = zinf(acc.z);
    acc.w = zinf(acc.w);
    out[(size_t)g * LPS + lane] = acc;
}

extern "C" void kernel_launch(void* const* d_in, const int* in_sizes, int n_in,
                              void* d_out, int out_size, void* d_ws, size_t ws_size,
                              hipStream_t stream) {
    const float* feat = (const float*)d_in[0];
    const int*   ids  = (const int*)d_in[1];
    float*       out  = (float*)d_out;

    const int N = in_sizes[0] / CCH;   // 4,000,000
    const int M = out_size    / CCH;   // 500,000

    const int threads = 256;

    if (ws_size >= (size_t)(M + 1) * sizeof(int)) {
        int* start = (int*)d_ws;
        int gridA = (N + 1 + threads - 1) / threads;
        seg_starts_kernel<<<gridA, threads, 0, stream>>>(ids, start, N, M);

        int totalB = M * LPS;
        int gridB = (totalB + threads - 1) / threads;
        seg_max_kernel<<<gridB, threads, 0, stream>>>(
            (const float4*)feat, start, (float4*)out, M);
    } else {
        int totalB = M * LPS;
        int gridB = (totalB + threads - 1) / threads;
        seg_max_search_kernel<<<gridB, threads, 0, stream>>>(
            (const float4*)feat, ids, (float4*)out, N, M);
    }
}

// Round 2
// 654.394 us; speedup vs baseline: 1.0508x; 1.0508x over previous
//
#include <hip/hip_runtime.h>
#include <math.h>

#define CCH 32   // channels
#define LPS 8    // lanes per segment (32 channels / 4 floats per lane)

typedef float f4 __attribute__((ext_vector_type(4)));

// Pass 1: start[s] = lower_bound(ids, s) for s in [0, M]
// Covers every s in [0, M]: s <= ids[0] from i==0; interior gaps from
// (ids[i-1], ids[i]]; s > ids[N-1] from i==N. d_ws is re-poisoned to 0xAA
// before every launch, so full coverage is required (and provided).
__global__ void seg_starts_kernel(const int* __restrict__ ids,
                                  int* __restrict__ start,
                                  int N, int M) {
    int i = blockIdx.x * blockDim.x + threadIdx.x;
    if (i > N) return;
    if (i == 0) {
        int hi = ids[0];
        for (int s = 0; s <= hi; ++s) start[s] = 0;
    } else if (i == N) {
        int lo = ids[N - 1];
        for (int s = lo + 1; s <= M; ++s) start[s] = N;
    } else {
        int prev = ids[i - 1];
        int cur  = ids[i];
        for (int s = prev + 1; s <= cur; ++s) start[s] = i;
    }
}

__device__ __forceinline__ f4 f4max(f4 a, f4 b) {
    f4 r;
    r.x = fmaxf(a.x, b.x);
    r.y = fmaxf(a.y, b.y);
    r.z = fmaxf(a.z, b.z);
    r.w = fmaxf(a.w, b.w);
    return r;
}

__device__ __forceinline__ float zinf(float v) {
    return isinf(v) ? 0.0f : v;
}

// Pass 2: one 8-lane group per segment; each lane owns 4 channels (f4).
// Unrolled x4: 4 independent nontemporal loads in flight per thread before
// the accumulate — MLP instead of a serial load->waitcnt->max chain.
__global__ void seg_max_kernel(const f4* __restrict__ feat,
                               const int* __restrict__ start,
                               f4* __restrict__ out, int M) {
    int t = blockIdx.x * blockDim.x + threadIdx.x;
    int g = t >> 3;        // segment id
    int lane = t & (LPS - 1);
    if (g >= M) return;

    int s0 = start[g];
    int s1 = start[g + 1];
    int n  = s1 - s0;

    f4 acc = {-INFINITY, -INFINITY, -INFINITY, -INFINITY};
    const f4* p = feat + (size_t)s0 * LPS + lane;

    int r = 0;
    for (; r + 4 <= n; r += 4) {
        f4 a = __builtin_nontemporal_load(p);
        f4 b = __builtin_nontemporal_load(p + LPS);
        f4 c = __builtin_nontemporal_load(p + 2 * LPS);
        f4 d = __builtin_nontemporal_load(p + 3 * LPS);
        acc = f4max(acc, f4max(f4max(a, b), f4max(c, d)));
        p += 4 * LPS;
    }
    for (; r < n; ++r) {
        acc = f4max(acc, __builtin_nontemporal_load(p));
        p += LPS;
    }

    acc.x = zinf(acc.x);
    acc.y = zinf(acc.y);
    acc.z = zinf(acc.z);
    acc.w = zinf(acc.w);
    __builtin_nontemporal_store(acc, out + (size_t)g * LPS + lane);
}

extern "C" void kernel_launch(void* const* d_in, const int* in_sizes, int n_in,
                              void* d_out, int out_size, void* d_ws, size_t ws_size,
                              hipStream_t stream) {
    const float* feat = (const float*)d_in[0];
    const int*   ids  = (const int*)d_in[1];
    float*       out  = (float*)d_out;

    const int N = in_sizes[0] / CCH;   // 4,000,000
    const int M = out_size    / CCH;   // 500,000

    const int threads = 256;

    int* start = (int*)d_ws;           // (M+1) ints; ws_size is ample
    int gridA = (N + 1 + threads - 1) / threads;
    seg_starts_kernel<<<gridA, threads, 0, stream>>>(ids, start, N, M);

    int totalB = M * LPS;
    int gridB = (totalB + threads - 1) / threads;
    seg_max_kernel<<<gridB, threads, 0, stream>>>(
        (const f4*)feat, start, (f4*)out, M);
}

// Round 3
// 653.715 us; speedup vs baseline: 1.0519x; 1.0010x over previous
//
#include <hip/hip_runtime.h>
#include <math.h>

#define CCH 32   // channels
#define LPS 8    // lanes per segment (32 channels / 4 floats per lane)

typedef float f4 __attribute__((ext_vector_type(4)));

// Pass 1: start[s] = lower_bound(ids, s) for s in [0, M]
__global__ void seg_starts_kernel(const int* __restrict__ ids,
                                  int* __restrict__ start,
                                  int N, int M) {
    int i = blockIdx.x * blockDim.x + threadIdx.x;
    if (i > N) return;
    if (i == 0) {
        int hi = ids[0];
        for (int s = 0; s <= hi; ++s) start[s] = 0;
    } else if (i == N) {
        int lo = ids[N - 1];
        for (int s = lo + 1; s <= M; ++s) start[s] = N;
    } else {
        int prev = ids[i - 1];
        int cur  = ids[i];
        for (int s = prev + 1; s <= cur; ++s) start[s] = i;
    }
}

__device__ __forceinline__ f4 f4max(f4 a, f4 b) {
    f4 r;
    r.x = fmaxf(a.x, b.x);
    r.y = fmaxf(a.y, b.y);
    r.z = fmaxf(a.z, b.z);
    r.w = fmaxf(a.w, b.w);
    return r;
}

__device__ __forceinline__ float zinf(float v) {
    return isinf(v) ? 0.0f : v;
}

// Load row (s0 + min(r, last)) for this lane; mask to -inf if r > last.
// Clamped duplicate loads hit the same cacheline as the last valid row
// (L1 hit, no extra HBM traffic); masking keeps the max exact.
__device__ __forceinline__ f4 ld_masked(const f4* __restrict__ base,
                                        int r, int last) {
    int rc = r < last ? r : last;
    f4 v = __builtin_nontemporal_load(base + rc * LPS);
    if (r > last) {
        f4 ninf = {-INFINITY, -INFINITY, -INFINITY, -INFINITY};
        v = ninf;
    }
    return v;
}

// Pass 2: one 8-lane group per segment; each lane owns 4 channels (f4).
// Branchless 8-wide body: 8 independent loads in flight per thread per
// iteration, no serial remainder chain.
__global__ void seg_max_kernel(const f4* __restrict__ feat,
                               const int* __restrict__ start,
                               f4* __restrict__ out, int M) {
    int t = blockIdx.x * blockDim.x + threadIdx.x;
    int g = t >> 3;        // segment id
    int lane = t & (LPS - 1);
    if (g >= M) return;

    int s0 = start[g];
    int s1 = start[g + 1];
    int n  = s1 - s0;
    int last = n - 1;                  // relative index of last valid row
    int iters = (n + 7) >> 3;

    f4 acc = {-INFINITY, -INFINITY, -INFINITY, -INFINITY};
    const f4* base = feat + (size_t)s0 * LPS + lane;

    for (int it = 0; it < iters; ++it) {
        int r = it << 3;
        f4 a = ld_masked(base, r + 0, last);
        f4 b = ld_masked(base, r + 1, last);
        f4 c = ld_masked(base, r + 2, last);
        f4 d = ld_masked(base, r + 3, last);
        f4 e = ld_masked(base, r + 4, last);
        f4 f = ld_masked(base, r + 5, last);
        f4 gg = ld_masked(base, r + 6, last);
        f4 h = ld_masked(base, r + 7, last);
        f4 m0 = f4max(f4max(a, b), f4max(c, d));
        f4 m1 = f4max(f4max(e, f), f4max(gg, h));
        acc = f4max(acc, f4max(m0, m1));
    }

    acc.x = zinf(acc.x);
    acc.y = zinf(acc.y);
    acc.z = zinf(acc.z);
    acc.w = zinf(acc.w);
    __builtin_nontemporal_store(acc, out + (size_t)g * LPS + lane);
}

extern "C" void kernel_launch(void* const* d_in, const int* in_sizes, int n_in,
                              void* d_out, int out_size, void* d_ws, size_t ws_size,
                              hipStream_t stream) {
    const float* feat = (const float*)d_in[0];
    const int*   ids  = (const int*)d_in[1];
    float*       out  = (float*)d_out;

    const int N = in_sizes[0] / CCH;   // 4,000,000
    const int M = out_size    / CCH;   // 500,000

    const int threads = 256;

    int* start = (int*)d_ws;           // (M+1) ints; ws_size is ample
    int gridA = (N + 1 + threads - 1) / threads;
    seg_starts_kernel<<<gridA, threads, 0, stream>>>(ids, start, N, M);

    int totalB = M * LPS;
    int gridB = (totalB + threads - 1) / threads;
    seg_max_kernel<<<gridB, threads, 0, stream>>>(
        (const f4*)feat, start, (f4*)out, M);
}